// Round 11
// baseline (96.662 us; speedup 1.0000x reference)
//
#include <hip/hip_runtime.h>

#define N 8000
#define C4 24
#define OCH 19
#define NCELL 1000
#define NCH 32
#define HSZ (NCH*NCELL)
#define U1 (1.0f/8000.0f)
#define CAND_CAP 1024

__device__ __forceinline__ int clamp10(int v) { return min(max(v, 0), 9); }

// ---- prep: B-side (0-31), A-side (32-63), w2 norms (64-95), w1 norms (96-127), init (128-129) ----
__global__ void __launch_bounds__(256) k_prep(
    const float* __restrict__ sf, const float* __restrict__ mf,
    const float* __restrict__ coords, const float* __restrict__ ori,
    const float* __restrict__ posses,
    float* __restrict__ w2, float* __restrict__ w1N,
    float4* __restrict__ alN, float4* __restrict__ oriN,
    int* __restrict__ cellB, int* __restrict__ histB,
    int* __restrict__ cellA, int* __restrict__ histA,
    int4* __restrict__ wn4, int* __restrict__ flags) {
    int bx = blockIdx.x, tid = threadIdx.x;
    if (bx < 32) {
        __shared__ int lhist[NCELL];
        __shared__ float sdiff[12];
        for (int c = tid; c < NCELL; c += 256) lhist[c] = 0;
        int j = bx*256 + tid;
        if (tid == 0) {
            double M[4][8];
            for (int r = 0; r < 4; ++r)
                for (int c = 0; c < 4; ++c) {
                    M[r][c] = (double)posses[16 + r*4 + c];
                    M[r][4+c] = (r == c) ? 1.0 : 0.0;
                }
            for (int col = 0; col < 4; ++col) {
                int piv = col; double best = fabs(M[col][col]);
                for (int r = col+1; r < 4; ++r) { double v = fabs(M[r][col]); if (v > best) { best = v; piv = r; } }
                if (piv != col) for (int c = 0; c < 8; ++c) { double t = M[col][c]; M[col][c] = M[piv][c]; M[piv][c] = t; }
                double inv = 1.0 / M[col][col];
                for (int c = 0; c < 8; ++c) M[col][c] *= inv;
                for (int r = 0; r < 4; ++r) if (r != col) {
                    double f = M[r][col];
                    for (int c = 0; c < 8; ++c) M[r][c] -= f * M[col][c];
                }
            }
            for (int r = 0; r < 3; ++r)
                for (int c = 0; c < 4; ++c) {
                    double sm = 0.0;
                    for (int k = 0; k < 4; ++k) sm += M[r][4+k] * (double)posses[k*4 + c];
                    sdiff[r*4 + c] = (float)sm;
                }
        }
        __syncthreads();
        if (j < N) {
            float c0 = coords[j*3], c1 = coords[j*3+1], c2 = coords[j*3+2];
            float a0 = (sdiff[0]*c0 + sdiff[1]*c1) + (sdiff[2]*c2 + sdiff[3]);
            float a1 = (sdiff[4]*c0 + sdiff[5]*c1) + (sdiff[6]*c2 + sdiff[7]);
            float a2 = (sdiff[8]*c0 + sdiff[9]*c1) + (sdiff[10]*c2 + sdiff[11]);
            alN[j] = make_float4(a0, a1, a2, a0*a0 + a1*a1 + a2*a2);
            int cx = clamp10((int)floorf((a0 + 25.f) * 0.2f));
            int cy = clamp10((int)floorf((a1 + 25.f) * 0.2f));
            int cz = clamp10((int)floorf((a2 + 25.f) * 0.2f));
            int cc = (cz*10 + cy)*10 + cx;
            cellB[j] = cc;
            atomicAdd(&lhist[cc], 1);
        }
        __syncthreads();
        for (int c = tid; c < NCELL; c += 256) histB[bx*NCELL + c] = lhist[c];
    } else if (bx < 64) {
        __shared__ int lhist[NCELL];
        for (int c = tid; c < NCELL; c += 256) lhist[c] = 0;
        __syncthreads();
        int i = (bx-32)*256 + tid;
        if (i < N) {
            float ox = ori[i*3], oy = ori[i*3+1], oz = ori[i*3+2];
            oriN[i] = make_float4(ox, oy, oz, ox*ox + oy*oy + oz*oz);
            int cx = clamp10((int)floorf((ox + 25.f) * 0.2f));
            int cy = clamp10((int)floorf((oy + 25.f) * 0.2f));
            int cz = clamp10((int)floorf((oz + 25.f) * 0.2f));
            int cc = (cz*10 + cy)*10 + cx;
            cellA[i] = cc;
            atomicAdd(&lhist[cc], 1);
        }
        __syncthreads();
        for (int c = tid; c < NCELL; c += 256) histA[(bx-32)*NCELL + c] = lhist[c];
    } else if (bx < 96) {
        int b = bx - 64;
        int u = tid & 3;
        #pragma unroll
        for (int p0 = 0; p0 < 256; p0 += 64) {
            int jp = b*256 + p0 + (tid >> 2);
            float ax = 0.f, ay = 0.f, az = 0.f, aw = 0.f;
            if (jp < N) {
                const float4* s4 = (const float4*)sf + jp*C4;
                #pragma unroll
                for (int s2 = 0; s2 < 6; ++s2) {
                    float4 v = s4[s2*4 + u];
                    ax += v.x*v.x; ay += v.y*v.y; az += v.z*v.z; aw += v.w*v.w;
                }
            }
            float pp = (ax + ay) + (az + aw);
            pp += __shfl_xor(pp, 1);
            pp += __shfl_xor(pp, 2);
            if (jp < N && u == 0) w2[jp] = sqrtf(pp);
        }
    } else if (bx < 128) {
        int b = bx - 96;
        int u = tid & 3;
        #pragma unroll
        for (int p0 = 0; p0 < 256; p0 += 64) {
            int ip = b*256 + p0 + (tid >> 2);
            float ax = 0.f, ay = 0.f, az = 0.f, aw = 0.f;
            if (ip < N) {
                const float4* s4 = (const float4*)mf + ip*C4;
                #pragma unroll
                for (int s2 = 0; s2 < 6; ++s2) {
                    float4 v = s4[s2*4 + u];
                    ax += v.x*v.x; ay += v.y*v.y; az += v.z*v.z; aw += v.w*v.w;
                }
            }
            float pp = (ax + ay) + (az + aw);
            pp += __shfl_xor(pp, 1);
            pp += __shfl_xor(pp, 2);
            if (ip < N && u == 0) w1N[ip] = sqrtf(pp);
        }
    } else {
        int t0 = (bx-128)*256 + tid;
        int4 f = make_int4(-1, -1, -1, -1);
        for (int t = t0; t < 4000; t += 512) wn4[t] = f;   // winnerHi|winnerLo 0xFF
        if (bx == 128 && tid < 8) flags[tid] = 0;
    }
}

// ---- scatter with in-block histogram scan: blocks 0-31 B-side, 32-63 A-side ----
__global__ void __launch_bounds__(256) k_scatter(
    const int* __restrict__ cellB, const int* __restrict__ histB,
    const int* __restrict__ cellA, const int* __restrict__ histA,
    const float* __restrict__ w2, const float4* __restrict__ alN, const float4* __restrict__ oriN,
    int* __restrict__ idBR, float* __restrict__ w2R, float4* __restrict__ alR, int* __restrict__ csB,
    int* __restrict__ idAR, float4* __restrict__ oriAR, int* __restrict__ csA) {
    __shared__ int sStart[NCELL];
    __shared__ int wtot[4];
    __shared__ int sc[256];
    int bx = blockIdx.x, tid = threadIdx.x;
    bool isB = bx < 32;
    int chunk = isB ? bx : bx - 32;
    const int* h = isB ? histB : histA;
    int* cs = isB ? csB : csA;

    int tot0 = 0, tot1 = 0, tot2 = 0, tot3 = 0;
    int pre0 = 0, pre1 = 0, pre2 = 0, pre3 = 0;
    bool cv = tid < 250;
    if (cv) {
        for (int ch = 0; ch < NCH; ++ch) {
            int4 v = ((const int4*)(h + ch*NCELL))[tid];
            tot0 += v.x; tot1 += v.y; tot2 += v.z; tot3 += v.w;
            if (ch < chunk) { pre0 += v.x; pre1 += v.y; pre2 += v.z; pre3 += v.w; }
        }
    }
    int S = tot0 + tot1 + tot2 + tot3;
    int lane = tid & 63, wv = tid >> 6;
    int x = S;
    for (int off = 1; off < 64; off <<= 1) { int y = __shfl_up(x, off); if (lane >= off) x += y; }
    if (lane == 63) wtot[wv] = x;
    __syncthreads();
    int wpre = 0;
    for (int k = 0; k < 4; ++k) if (k < wv) wpre += wtot[k];
    int run = wpre + x - S;
    if (cv) {
        int c = tid*4;
        sStart[c]   = run + pre0; if (chunk == 0) cs[c]   = run; run += tot0;
        sStart[c+1] = run + pre1; if (chunk == 0) cs[c+1] = run; run += tot1;
        sStart[c+2] = run + pre2; if (chunk == 0) cs[c+2] = run; run += tot2;
        sStart[c+3] = run + pre3; if (chunk == 0) cs[c+3] = run; run += tot3;
    }
    if (chunk == 0 && tid == 0) cs[NCELL] = N;

    int gi = chunk*256 + tid;
    const int* cellArr = isB ? cellB : cellA;
    int cell = (gi < N) ? cellArr[gi] : -1;
    sc[tid] = cell;
    __syncthreads();
    if (gi >= N) return;
    int rank = 0;
    const int4* sc4 = (const int4*)sc;
    int full = tid >> 2;
    for (int t4 = 0; t4 < full; ++t4) {
        int4 q = sc4[t4];
        rank += (q.x == cell) + (q.y == cell) + (q.z == cell) + (q.w == cell);
    }
    for (int t = full*4; t < tid; ++t) rank += (sc[t] == cell);
    int pos = sStart[cell] + rank;
    if (isB) {
        idBR[pos] = gi;
        w2R[pos] = w2[gi];
        alR[pos] = alN[gi];
    } else {
        idAR[pos] = gi;
        oriAR[pos] = oriN[gi];
    }
}

// ---- pass1: per-row sums (round-10 pair kernel, atomic tail removed) -> bvec ----
__global__ void __launch_bounds__(256) k_pass1(
    const float4* __restrict__ mf4, const float* __restrict__ ori,
    const float* __restrict__ w1N,
    const float4* __restrict__ alR, const float* __restrict__ w2R,
    const float4* __restrict__ sf4, const int* __restrict__ idBR,
    const int* __restrict__ csB,
    float* __restrict__ bvec) {
    __shared__ float4 sRow[4][C4];
    __shared__ int bgi[4][128];
    __shared__ float bc[4][128];
    __shared__ float bw[4][128];

    int tid = threadIdx.x, lane = tid & 63, w = tid >> 6;
    int i = blockIdx.x * 4 + w;
    if (lane < C4) sRow[w][lane] = mf4[i*C4 + lane];
    __syncthreads();

    float ox = ori[i*3], oy = ori[i*3+1], oz = ori[i*3+2];
    float xnv = ox*ox + oy*oy + oz*oz;
    float w1v = w1N[i];

    int cx = clamp10((int)floorf((ox + 25.f) * 0.2f));
    int cy = clamp10((int)floorf((oy + 25.f) * 0.2f));
    int cz = clamp10((int)floorf((oz + 25.f) * 0.2f));
    int xlo = max(cx-1, 0), xhi = min(cx+1, 9);

    int s_[9], l_[9], c_[9];
    int tot = 0;
    #pragma unroll
    for (int t = 0; t < 9; ++t) {
        int z = cz + (t/3) - 1, y = cy + (t%3) - 1;
        bool ok = ((unsigned)z <= 9u) && ((unsigned)y <= 9u);
        int ss = 0, ee = 0;
        if (ok) {
            int cbase = (z*10 + y)*10;
            ss = csB[cbase + xlo];
            ee = csB[cbase + xhi + 1];
        }
        s_[t] = ss; l_[t] = ee - ss; c_[t] = tot; tot += ee - ss;
    }

    auto calcq = [&](int f) -> int {
        int q = 0;
        #pragma unroll
        for (int t = 0; t < 9; ++t) {
            bool in = (f >= c_[t]) && (f - c_[t] < l_[t]);
            if (in) q = s_[t] + (f - c_[t]);
        }
        return q;
    };

    int cnt = 0, done = 0;
    float racc = 0.f;
    unsigned long long lmask = (lane == 0) ? 0ull : (~0ull >> (64 - lane));
    int gu = lane & 3, gt_ = lane >> 2;

    auto process16 = [&](int nb) {
        int slot = (done + gt_) & 127;
        int gi = bgi[w][slot];
        float cdb = bc[w][slot];
        float w2v = bw[w][slot];
        float dotp = 0.f;
        if (gt_ < nb) {
            const float4* br = sf4 + gi*C4;
            float ax = 0.f, ay = 0.f, az = 0.f, aw = 0.f;
            #pragma unroll
            for (int s2 = 0; s2 < 6; ++s2) {
                int kk = s2*4 + gu;
                float4 a = sRow[w][kk];
                float4 b = br[kk];
                ax += a.x*b.x; ay += a.y*b.y; az += a.z*b.z; aw += a.w*b.w;
            }
            dotp = (ax + ay) + (az + aw);
        }
        dotp += __shfl_xor(dotp, 1);
        dotp += __shfl_xor(dotp, 2);
        if (gt_ < nb && gu == 0) {
            float fdc = 1.f - dotp / fmaxf(w1v * w2v, 1e-8f);
            float dist = (1.f + fdc) - expf(-0.5f * cdb);
            float K = expf(-dist / 0.03f);
            racc += K * U1;
        }
        done += nb;
    };

    bool act_cur = lane < tot;
    float4 aj_cur = make_float4(0.f, 0.f, 0.f, 0.f);
    int gi_cur = 0; float w2_cur = 0.f;
    if (act_cur) {
        int q = calcq(lane);
        aj_cur = alR[q]; gi_cur = idBR[q]; w2_cur = w2R[q];
    }
    for (int f0 = 0; f0 < tot; f0 += 64) {
        int fn = f0 + 64 + lane;
        bool act_n = fn < tot;
        float4 aj_n = make_float4(0.f, 0.f, 0.f, 0.f);
        int gi_n = 0; float w2_n = 0.f;
        if (act_n) {
            int qn = calcq(fn);
            aj_n = alR[qn]; gi_n = idBR[qn]; w2_n = w2R[qn];
        }
        bool pass = false; float cdv = 0.f;
        if (act_cur) {
            float d = xnv + aj_cur.w - 2.f*(ox*aj_cur.x + oy*aj_cur.y + oz*aj_cur.z);
            cdv = fmaxf(d, 0.f) * 4.f;
            pass = cdv < 100.f;
        }
        unsigned long long m = __ballot(pass);
        if (pass) {
            int slot = (cnt + __popcll(m & lmask)) & 127;
            bgi[w][slot] = gi_cur; bc[w][slot] = cdv; bw[w][slot] = w2_cur;
        }
        cnt += __popcll(m);
        if (cnt - done >= 64) {
            process16(16); process16(16); process16(16); process16(16);
        }
        aj_cur = aj_n; gi_cur = gi_n; w2_cur = w2_n; act_cur = act_n;
    }
    while (cnt > done) {
        int nb = cnt - done; if (nb > 16) nb = 16;
        process16(nb);
    }

    for (int off = 32; off; off >>= 1) racc += __shfl_xor(racc, off);
    if (lane == 0) bvec[i] = U1 / (racc + 1e-16f);
}

// ---- pass2: column-owned max (zero colkey atomics) + fused post ----
__global__ void __launch_bounds__(256) k_pass2(
    const float4* __restrict__ mf4, const float4* __restrict__ sf4,
    const int* __restrict__ idAR, const float4* __restrict__ oriAR, const int* __restrict__ csA,
    const int* __restrict__ idBR, const float4* __restrict__ alR, const float* __restrict__ w2R,
    const int* __restrict__ csB,
    const float* __restrict__ w1N, const float* __restrict__ bvec,
    const float* __restrict__ sv_prob, const int* __restrict__ gt,
    int* __restrict__ winnerHi, int* __restrict__ winnerLo, int* __restrict__ flags) {
    __shared__ float4 sColF[16][C4];
    __shared__ float4 sColAl[16];
    __shared__ float  sColW2[16];
    __shared__ int    sColJ[16];
    __shared__ float4 sCandOri[CAND_CAP];
    __shared__ int    sCandGi[CAND_CAP];
    __shared__ float  sCandW1[CAND_CAP];
    __shared__ float  sCandB[CAND_CAP];
    __shared__ unsigned long long sBest[16][4];
    __shared__ int    rq[4][128];
    __shared__ float  rc[4][128];

    int cell = blockIdx.x;
    int rB0 = csB[cell] + blockIdx.y * 16;
    int rB1 = min(csB[cell+1], rB0 + 16);
    if (rB0 >= rB1) return;
    int nC = rB1 - rB0;
    int tid = threadIdx.x, lane = tid & 63, w = tid >> 6;

    if (tid < nC) {
        sColJ[tid] = idBR[rB0 + tid];
        sColAl[tid] = alR[rB0 + tid];
        sColW2[tid] = w2R[rB0 + tid];
    }
    if (tid < 64) ((unsigned long long*)sBest)[tid] = 0ull;
    __syncthreads();
    for (int idx = tid; idx < nC*C4; idx += 256) {
        int c = idx / C4, kk = idx - c*C4;
        sColF[c][kk] = sf4[sColJ[c]*C4 + kk];
    }

    // A-side candidate segments around this B-cell (support symmetric: |dcell|<=1)
    int cx = cell % 10, cy = (cell/10) % 10, cz = cell/100;
    int xlo = max(cx-1, 0), xhi = min(cx+1, 9);
    int s_[9], l_[9], c_[9]; int tot = 0;
    #pragma unroll
    for (int t = 0; t < 9; ++t) {
        int z = cz + t/3 - 1, y = cy + t%3 - 1;
        bool ok = ((unsigned)z <= 9u) && ((unsigned)y <= 9u);
        int ss = 0, ee = 0;
        if (ok) { int cb = (z*10 + y)*10; ss = csA[cb + xlo]; ee = csA[cb + xhi + 1]; }
        s_[t] = ss; l_[t] = ee - ss; c_[t] = tot; tot += ee - ss;
    }
    for (int f = tid; f < tot; f += 256) {
        int q = 0;
        #pragma unroll
        for (int t = 0; t < 9; ++t) {
            bool in = (f >= c_[t]) && (f - c_[t] < l_[t]);
            if (in) q = s_[t] + (f - c_[t]);
        }
        if (f < CAND_CAP) {
            int gi = idAR[q];
            sCandOri[f] = oriAR[q];
            sCandGi[f] = gi;
            sCandW1[f] = w1N[gi];
            sCandB[f] = bvec[gi];
        }
    }
    __syncthreads();
    if (tot > CAND_CAP) tot = CAND_CAP;   // unreachable for this data (E=420, cap=+29 sigma)

    unsigned long long lmask = lane ? (~0ull >> (64 - lane)) : 0ull;
    int gu = lane & 3, gt_ = lane >> 2;

    for (int c = 0; c < nC; ++c) {
        float4 aj = sColAl[c];
        float w2v = sColW2[c];
        unsigned long long bestk = 0ull;
        int cnt = 0, done = 0;

        auto process16 = [&](int nb) {
            int sl = (done + gt_) & 127;
            int slot = rq[w][sl];
            float cdb = rc[w][sl];
            float dotp = 0.f;
            int gi = 0; float w1v = 0.f, bv = 0.f;
            if (gt_ < nb) {
                gi = sCandGi[slot]; w1v = sCandW1[slot]; bv = sCandB[slot];
                const float4* ar = mf4 + gi*C4;
                float ax = 0.f, ay = 0.f, az = 0.f, aw = 0.f;
                #pragma unroll
                for (int s2 = 0; s2 < 6; ++s2) {
                    int kk = s2*4 + gu;
                    float4 a = ar[kk];            // row (mean_feat) — same operand role as pass1
                    float4 b = sColF[c][kk];      // column (sur_feat)
                    ax += a.x*b.x; ay += a.y*b.y; az += a.z*b.z; aw += a.w*b.w;
                }
                dotp = (ax + ay) + (az + aw);
            }
            dotp += __shfl_xor(dotp, 1);
            dotp += __shfl_xor(dotp, 2);
            unsigned long long mykey = 0ull;
            if (gt_ < nb && gu == 0) {
                float fdc = 1.f - dotp / fmaxf(w1v * w2v, 1e-8f);
                float dist = (1.f + fdc) - expf(-0.5f * cdb);
                float K = expf(-dist / 0.03f);
                float val = K * bv;
                if (val > 0.f)
                    mykey = ((unsigned long long)__float_as_uint(val) << 32) | (unsigned)(N - gi);
            }
            for (int off = 1; off < 64; off <<= 1) {
                unsigned long long o = __shfl_xor(mykey, off);
                if (o > mykey) mykey = o;
            }
            if (mykey > bestk) bestk = mykey;
            done += nb;
        };

        for (int f0 = w*64; f0 < tot; f0 += 256) {
            int f = f0 + lane;
            bool pass = false; float cdv = 0.f;
            if (f < tot) {
                float4 oi = sCandOri[f];
                float d = oi.w + aj.w - 2.f*(oi.x*aj.x + oi.y*aj.y + oi.z*aj.z);
                cdv = fmaxf(d, 0.f) * 4.f;
                pass = cdv < 100.f;
            }
            unsigned long long m = __ballot(pass);
            if (pass) {
                int sl = (cnt + __popcll(m & lmask)) & 127;
                rq[w][sl] = f; rc[w][sl] = cdv;
            }
            cnt += __popcll(m);
            while (cnt - done >= 16) process16(16);
        }
        while (cnt > done) {
            int nb = cnt - done; if (nb > 16) nb = 16;
            process16(nb);
        }
        if (lane == 0) sBest[c][w] = bestk;
    }
    __syncthreads();

    // fused post: decode per-column winner, gather softmax prob, winner/flags
    bool valid = tid < nC;
    float vv = 0.f; int bidx = 0, jn = 0;
    if (valid) {
        unsigned long long k0 = sBest[tid][0], k1 = sBest[tid][1];
        unsigned long long k2 = sBest[tid][2], k3 = sBest[tid][3];
        unsigned long long km = k0; if (k1 > km) km = k1; if (k2 > km) km = k2; if (k3 > km) km = k3;
        bidx = km ? (N - (int)(km & 0xffffffffull)) : 0;
        jn = sColJ[tid];
        const float* p = sv_prob + bidx*OCH;
        float m = -1e30f;
        for (int c = 0; c < OCH; ++c) m = fmaxf(m, p[c]);
        float ssum = 0.f, eg = 0.f; int g = gt[jn];
        for (int c = 0; c < OCH; ++c) { float e = expf(p[c] - m); ssum += e; if (c == g) eg = e; }
        vv = eg / ssum;
    }
    bool hi = valid && (vv > 0.1f);
    bool nothi = valid && !(vv > 0.1f);
    bool lo = valid && (vv > 0.0f);
    bool notlo = valid && !(vv > 0.0f);
    if (hi) atomicMax(&winnerHi[bidx], jn);
    if (lo) atomicMax(&winnerLo[bidx], jn);
    unsigned long long m0 = __ballot(hi);
    unsigned long long m1 = __ballot(nothi);
    unsigned long long m2 = __ballot(notlo);
    if (lane == 0 && w == 0) {
        if (m0) atomicOr(&flags[0], 1);
        if (m1) atomicOr(&flags[1], 1);
        if (m2) atomicOr(&flags[2], 1);
    }
}

// ---- final: blocks 0-7 rowsout, block 8 trust, blocks 9+ passthrough copies ----
__global__ void __launch_bounds__(1024) k_final(
    const int* __restrict__ winnerHi, const int* __restrict__ winnerLo,
    const int* __restrict__ flags, const int* __restrict__ gt,
    const float* __restrict__ sv_prob,
    const float* __restrict__ mf, const float* __restrict__ ori,
    float* __restrict__ o_svp, float* __restrict__ o_pre,
    float* __restrict__ out0, float* __restrict__ out5,
    float* __restrict__ o_mf, float* __restrict__ o_ori) {
    int bx = blockIdx.x, tid = threadIdx.x;
    if (bx < 8) {
        const int* winner = flags[0] ? winnerHi : winnerLo;
        int i = bx*1024 + tid;
        if (i >= N) return;
        int w = winner[i];
        if (w >= 0) {
            int g = gt[w];
            for (int c = 0; c < OCH; ++c) o_svp[i*OCH + c] = (c == g) ? 1.f : 0.f;
            o_pre[i] = (float)g;
        } else {
            const float* p = sv_prob + i*OCH;
            float m = -1e30f;
            for (int c = 0; c < OCH; ++c) m = fmaxf(m, p[c]);
            float e[OCH]; float ssum = 0.f;
            for (int c = 0; c < OCH; ++c) { e[c] = expf(p[c] - m); ssum += e[c]; }
            float best = e[0] / ssum; int pidx = 0;
            o_svp[i*OCH] = best;
            for (int c = 1; c < OCH; ++c) {
                float r = e[c] / ssum;
                o_svp[i*OCH + c] = r;
                if (r > best) { best = r; pidx = c; }
            }
            o_pre[i] = (float)pidx;
        }
    } else if (bx == 8) {
        __shared__ int wsum[16];
        const int* winner = flags[0] ? winnerHi : winnerLo;
        int off = flags[0] ? (flags[1] ? 1 : 0) : (flags[2] ? 1 : 0);
        for (int p = tid; p < N; p += 1024) { out0[p] = -1.f; out5[p] = -1.f; }
        __syncthreads();
        int base = 0;
        for (int round = 0; round < N; round += 1024) {
            int i = round + tid;
            int pres = (i < N && winner[i] >= 0) ? 1 : 0;
            unsigned long long mask = __ballot(pres);
            int lane = tid & 63;
            int wv = tid >> 6;
            int excl = (lane == 0) ? 0 : __popcll(mask & (~0ull >> (64 - lane)));
            if (lane == 0) wsum[wv] = __popcll(mask);
            __syncthreads();
            int wpre = 0, tot = 0;
            for (int t = 0; t < 16; ++t) { if (t < wv) wpre += wsum[t]; tot += wsum[t]; }
            int pos = base + wpre + excl + off;
            if (pres && pos < N) { out0[pos] = (float)i; out5[pos] = (float)i; }
            base += tot;
            __syncthreads();
        }
    } else {
        const float4* mf4 = (const float4*)mf;
        const float4* ori4 = (const float4*)ori;
        float4* omf4 = (float4*)o_mf;
        float4* oori4 = (float4*)o_ori;
        int t0 = (bx-9)*1024 + tid;
        for (int t = t0; t < 198000; t += 51*1024) {
            if (t < 192000) omf4[t] = mf4[t];
            else oori4[t-192000] = ori4[t-192000];
        }
    }
}

// ---- launch ----
extern "C" void kernel_launch(void* const* d_in, const int* in_sizes, int n_in,
                              void* d_out, int out_size, void* d_ws, size_t ws_size,
                              hipStream_t stream) {
    const float* sur_feat   = (const float*)d_in[0];
    const float* sur_coords = (const float*)d_in[1];
    const int*   sur_gt     = (const int*)d_in[2];
    const float* sv_prob    = (const float*)d_in[3];
    const float* mean_feat  = (const float*)d_in[4];
    const float* ori        = (const float*)d_in[5];
    const float* posses     = (const float*)d_in[6];

    float* out = (float*)d_out;
    float* o_trust  = out;
    float* o_mf     = out + 8000;
    float* o_ori    = out + 776000;
    float* o_pre    = out + 800000;
    float* o_svp    = out + 808000;
    float* o_trust2 = out + 960000;

    float* w = (float*)d_ws;
    // 16B-aligned region
    float4* alN = (float4*)w;      w += 4*N;
    float4* oriN = (float4*)w;     w += 4*N;
    float4* alR = (float4*)w;      w += 4*N;
    float4* oriAR = (float4*)w;    w += 4*N;
    // scalar region
    float* w2 = w;                 w += N;
    float* w1N = w;                w += N;
    float* w2R = w;                w += N;
    float* bvec = w;               w += N;
    int* cellB = (int*)w;          w += N;
    int* cellA = (int*)w;          w += N;
    int* histB = (int*)w;          w += HSZ;
    int* histA = (int*)w;          w += HSZ;
    int* flags = (int*)w;          w += 8;
    int* csB = (int*)w;            w += 1008;
    int* csA = (int*)w;            w += 1008;
    int* idBR = (int*)w;           w += N;
    int* idAR = (int*)w;           w += N;
    int* winnerHi = (int*)w;       w += N;   // contiguous with winnerLo (int4-inited)
    int* winnerLo = (int*)w;       w += N;

    dim3 b256(256);

    k_prep<<<130, b256, 0, stream>>>(sur_feat, mean_feat, sur_coords, ori, posses,
                                     w2, w1N, alN, oriN, cellB, histB, cellA, histA,
                                     (int4*)winnerHi, flags);
    k_scatter<<<64, b256, 0, stream>>>(cellB, histB, cellA, histA, w2, alN, oriN,
                                       idBR, w2R, alR, csB, idAR, oriAR, csA);
    k_pass1<<<N/4, b256, 0, stream>>>((const float4*)mean_feat, ori, w1N, alR, w2R,
                                      (const float4*)sur_feat, idBR, csB, bvec);
    k_pass2<<<dim3(NCELL, 4), b256, 0, stream>>>((const float4*)mean_feat, (const float4*)sur_feat,
                                                 idAR, oriAR, csA, idBR, alR, w2R, csB,
                                                 w1N, bvec, sv_prob, sur_gt,
                                                 winnerHi, winnerLo, flags);
    k_final<<<60, 1024, 0, stream>>>(winnerHi, winnerLo, flags, sur_gt, sv_prob,
                                     mean_feat, ori,
                                     o_svp, o_pre, o_trust, o_trust2, o_mf, o_ori);
}

// Round 12
// 63.015 us; speedup vs baseline: 1.5340x; 1.5340x over previous
//
#include <hip/hip_runtime.h>

#define N 8000
#define C4 24
#define OCH 19
#define NCELL 1000
#define NCH 32
#define HSZ (NCH*NCELL)
#define U1 (1.0f/8000.0f)
#define PAIR_CAP 256
#define NREP 8

__device__ __forceinline__ int clamp10(int v) { return min(max(v, 0), 9); }

// ---------------- prep: cell/hist (0-31), cooperative w2 norms (32-63), ws init (64-79) ----------------
__global__ void __launch_bounds__(256) k_prep(
    const float* __restrict__ sf, const float* __restrict__ coords,
    const float* __restrict__ posses,
    float* __restrict__ w2, float4* __restrict__ alN,
    int* __restrict__ cellB, int* __restrict__ histB,
    int4* __restrict__ ck4, int4* __restrict__ wn4, int* __restrict__ flags) {
    int bx = blockIdx.x, tid = threadIdx.x;
    if (bx < 32) {
        __shared__ int lhist[NCELL];
        __shared__ float sdiff[12];
        for (int c = tid; c < NCELL; c += 256) lhist[c] = 0;
        int j = bx*256 + tid;
        if (tid == 0) {
            double M[4][8];
            for (int r = 0; r < 4; ++r)
                for (int c = 0; c < 4; ++c) {
                    M[r][c] = (double)posses[16 + r*4 + c];
                    M[r][4+c] = (r == c) ? 1.0 : 0.0;
                }
            for (int col = 0; col < 4; ++col) {
                int piv = col; double best = fabs(M[col][col]);
                for (int r = col+1; r < 4; ++r) { double v = fabs(M[r][col]); if (v > best) { best = v; piv = r; } }
                if (piv != col) for (int c = 0; c < 8; ++c) { double t = M[col][c]; M[col][c] = M[piv][c]; M[piv][c] = t; }
                double inv = 1.0 / M[col][col];
                for (int c = 0; c < 8; ++c) M[col][c] *= inv;
                for (int r = 0; r < 4; ++r) if (r != col) {
                    double f = M[r][col];
                    for (int c = 0; c < 8; ++c) M[r][c] -= f * M[col][c];
                }
            }
            for (int r = 0; r < 3; ++r)
                for (int c = 0; c < 4; ++c) {
                    double sm = 0.0;
                    for (int k = 0; k < 4; ++k) sm += M[r][4+k] * (double)posses[k*4 + c];
                    sdiff[r*4 + c] = (float)sm;
                }
        }
        __syncthreads();
        if (j < N) {
            float c0 = coords[j*3], c1 = coords[j*3+1], c2 = coords[j*3+2];
            float a0 = (sdiff[0]*c0 + sdiff[1]*c1) + (sdiff[2]*c2 + sdiff[3]);
            float a1 = (sdiff[4]*c0 + sdiff[5]*c1) + (sdiff[6]*c2 + sdiff[7]);
            float a2 = (sdiff[8]*c0 + sdiff[9]*c1) + (sdiff[10]*c2 + sdiff[11]);
            alN[j] = make_float4(a0, a1, a2, a0*a0 + a1*a1 + a2*a2);
            int cx = clamp10((int)floorf((a0 + 25.f) * 0.2f));
            int cy = clamp10((int)floorf((a1 + 25.f) * 0.2f));
            int cz = clamp10((int)floorf((a2 + 25.f) * 0.2f));
            int cc = (cz*10 + cy)*10 + cx;
            cellB[j] = cc;
            atomicAdd(&lhist[cc], 1);   // LDS atomic: deterministic count
        }
        __syncthreads();
        for (int c = tid; c < NCELL; c += 256) histB[bx*NCELL + c] = lhist[c];  // [chunk][cell], coalesced
    } else if (bx < 64) {
        // cooperative feature norms: 4 lanes per point, fully-consumed cachelines
        int b = bx - 32;
        int u = tid & 3;
        #pragma unroll
        for (int p0 = 0; p0 < 256; p0 += 64) {
            int jp = b*256 + p0 + (tid >> 2);
            float ax = 0.f, ay = 0.f, az = 0.f, aw = 0.f;
            if (jp < N) {
                const float4* s4 = (const float4*)sf + jp*C4;
                #pragma unroll
                for (int s2 = 0; s2 < 6; ++s2) {
                    float4 v = s4[s2*4 + u];
                    ax += v.x*v.x; ay += v.y*v.y; az += v.z*v.z; aw += v.w*v.w;
                }
            }
            float pp = (ax + ay) + (az + aw);
            pp += __shfl_xor(pp, 1);
            pp += __shfl_xor(pp, 2);
            if (jp < N && u == 0) w2[jp] = sqrtf(pp);
        }
    } else {
        // init: colkeyR zero (NREP*N u64 = 32000 int4) | winnerHi/Lo 0xFF (4000 int4) | flags
        int t0 = (bx-64)*256 + tid;
        int4 z = make_int4(0, 0, 0, 0);
        int4 f = make_int4(-1, -1, -1, -1);
        for (int t = t0; t < 36000; t += 16*256) {
            if (t < 32000) ck4[t] = z;
            else wn4[t-32000] = f;
        }
        if (bx == 64 && tid < 8) flags[tid] = 0;
    }
}

// ---------------- scatter with in-block histogram scan ----------------
__global__ void __launch_bounds__(256) k_scatter(
    const int* __restrict__ cellB, const int* __restrict__ h,
    const float* __restrict__ w2, const float4* __restrict__ alN,
    int* __restrict__ idBR, float* __restrict__ w2R, float4* __restrict__ alR,
    int* __restrict__ csB) {
    __shared__ int sStart[NCELL];
    __shared__ int wtot[4];
    __shared__ int sc[256];
    int chunk = blockIdx.x, tid = threadIdx.x;

    int tot0 = 0, tot1 = 0, tot2 = 0, tot3 = 0;
    int pre0 = 0, pre1 = 0, pre2 = 0, pre3 = 0;
    bool cv = tid < 250;
    if (cv) {
        for (int ch = 0; ch < NCH; ++ch) {
            int4 v = ((const int4*)(h + ch*NCELL))[tid];   // coalesced int4
            tot0 += v.x; tot1 += v.y; tot2 += v.z; tot3 += v.w;
            if (ch < chunk) { pre0 += v.x; pre1 += v.y; pre2 += v.z; pre3 += v.w; }
        }
    }
    int S = tot0 + tot1 + tot2 + tot3;
    int lane = tid & 63, wv = tid >> 6;
    int x = S;
    for (int off = 1; off < 64; off <<= 1) { int y = __shfl_up(x, off); if (lane >= off) x += y; }
    if (lane == 63) wtot[wv] = x;
    __syncthreads();
    int wpre = 0;
    for (int k = 0; k < 4; ++k) if (k < wv) wpre += wtot[k];
    int run = wpre + x - S;
    if (cv) {
        int c = tid*4;
        sStart[c]   = run + pre0; if (chunk == 0) csB[c]   = run; run += tot0;
        sStart[c+1] = run + pre1; if (chunk == 0) csB[c+1] = run; run += tot1;
        sStart[c+2] = run + pre2; if (chunk == 0) csB[c+2] = run; run += tot2;
        sStart[c+3] = run + pre3; if (chunk == 0) csB[c+3] = run; run += tot3;
    }
    if (chunk == 0 && tid == 0) csB[NCELL] = N;

    int gi = chunk*256 + tid;
    int cell = (gi < N) ? cellB[gi] : -1;
    sc[tid] = cell;
    __syncthreads();
    if (gi >= N) return;
    int rank = 0;
    const int4* sc4 = (const int4*)sc;
    int full = tid >> 2;
    for (int t4 = 0; t4 < full; ++t4) {
        int4 q = sc4[t4];
        rank += (q.x == cell) + (q.y == cell) + (q.z == cell) + (q.w == cell);
    }
    for (int t = full*4; t < tid; ++t) rank += (sc[t] == cell);
    int pos = sStart[cell] + rank;
    idBR[pos] = gi;
    w2R[pos] = w2[gi];
    alR[pos] = alN[gi];
}

// ---------------- pair pass (round-10 core) with NREP-replicated colkey atomics ----------------
__global__ void __launch_bounds__(256) k_pairs(
    const float4* __restrict__ mf4, const float* __restrict__ ori,
    const float4* __restrict__ alR, const float* __restrict__ w2R,
    const float4* __restrict__ sf4, const int* __restrict__ idBR,
    const int* __restrict__ csB,
    unsigned long long* __restrict__ colkeyR) {
    __shared__ float4 sRow[4][C4];
    __shared__ int bgi[4][128];
    __shared__ float bc[4][128];
    __shared__ float bw[4][128];
    __shared__ int sJ[4][PAIR_CAP];
    __shared__ float sK[4][PAIR_CAP];

    int tid = threadIdx.x, lane = tid & 63, w = tid >> 6;
    int i = blockIdx.x * 4 + w;
    if (lane < C4) sRow[w][lane] = mf4[i*C4 + lane];
    __syncthreads();

    float ox = ori[i*3], oy = ori[i*3+1], oz = ori[i*3+2];
    float xnv = ox*ox + oy*oy + oz*oz;
    float s = 0.f;
    for (int kk = 0; kk < C4; ++kk) {
        float4 v = sRow[w][kk];
        s += v.x*v.x; s += v.y*v.y; s += v.z*v.z; s += v.w*v.w;
    }
    float w1v = sqrtf(s);

    int cx = clamp10((int)floorf((ox + 25.f) * 0.2f));
    int cy = clamp10((int)floorf((oy + 25.f) * 0.2f));
    int cz = clamp10((int)floorf((oz + 25.f) * 0.2f));
    int xlo = max(cx-1, 0), xhi = min(cx+1, 9);

    int s_[9], l_[9], c_[9];
    int tot = 0;
    #pragma unroll
    for (int t = 0; t < 9; ++t) {
        int z = cz + (t/3) - 1, y = cy + (t%3) - 1;
        bool ok = ((unsigned)z <= 9u) && ((unsigned)y <= 9u);
        int ss = 0, ee = 0;
        if (ok) {
            int cbase = (z*10 + y)*10;
            ss = csB[cbase + xlo];
            ee = csB[cbase + xhi + 1];
        }
        s_[t] = ss; l_[t] = ee - ss; c_[t] = tot; tot += ee - ss;
    }

    auto calcq = [&](int f) -> int {
        int q = 0;
        #pragma unroll
        for (int t = 0; t < 9; ++t) {
            bool in = (f >= c_[t]) && (f - c_[t] < l_[t]);
            if (in) q = s_[t] + (f - c_[t]);
        }
        return q;
    };

    int cnt = 0, done = 0, npairs = 0;
    float racc = 0.f;
    unsigned long long lmask = (lane == 0) ? 0ull : (~0ull >> (64 - lane));
    int gu = lane & 3, gt_ = lane >> 2;

    auto process16 = [&](int nb) {
        int slot = (done + gt_) & 127;
        int gi = bgi[w][slot];
        float cdb = bc[w][slot];
        float w2v = bw[w][slot];
        float dotp = 0.f;
        if (gt_ < nb) {
            const float4* br = sf4 + gi*C4;
            float ax = 0.f, ay = 0.f, az = 0.f, aw = 0.f;
            #pragma unroll
            for (int s2 = 0; s2 < 6; ++s2) {
                int kk = s2*4 + gu;
                float4 a = sRow[w][kk];
                float4 b = br[kk];
                ax += a.x*b.x; ay += a.y*b.y; az += a.z*b.z; aw += a.w*b.w;
            }
            dotp = (ax + ay) + (az + aw);
        }
        dotp += __shfl_xor(dotp, 1);
        dotp += __shfl_xor(dotp, 2);
        if (gt_ < nb && gu == 0) {
            float fdc = 1.f - dotp / fmaxf(w1v * w2v, 1e-8f);
            float dist = (1.f + fdc) - expf(-0.5f * cdb);
            float K = expf(-dist / 0.03f);
            racc += K * U1;
            int sl = npairs + gt_;
            if (sl < PAIR_CAP) { sJ[w][sl] = gi; sK[w][sl] = K; }
        }
        npairs += nb;
        done += nb;
    };

    bool act_cur = lane < tot;
    float4 aj_cur = make_float4(0.f, 0.f, 0.f, 0.f);
    int gi_cur = 0; float w2_cur = 0.f;
    if (act_cur) {
        int q = calcq(lane);
        aj_cur = alR[q]; gi_cur = idBR[q]; w2_cur = w2R[q];
    }
    for (int f0 = 0; f0 < tot; f0 += 64) {
        int fn = f0 + 64 + lane;
        bool act_n = fn < tot;
        float4 aj_n = make_float4(0.f, 0.f, 0.f, 0.f);
        int gi_n = 0; float w2_n = 0.f;
        if (act_n) {
            int qn = calcq(fn);
            aj_n = alR[qn]; gi_n = idBR[qn]; w2_n = w2R[qn];
        }
        bool pass = false; float cdv = 0.f;
        if (act_cur) {
            float d = xnv + aj_cur.w - 2.f*(ox*aj_cur.x + oy*aj_cur.y + oz*aj_cur.z);
            cdv = fmaxf(d, 0.f) * 4.f;
            pass = cdv < 100.f;
        }
        unsigned long long m = __ballot(pass);
        if (pass) {
            int slot = (cnt + __popcll(m & lmask)) & 127;
            bgi[w][slot] = gi_cur; bc[w][slot] = cdv; bw[w][slot] = w2_cur;
        }
        cnt += __popcll(m);
        if (cnt - done >= 64) {
            process16(16); process16(16); process16(16); process16(16);
        }
        aj_cur = aj_n; gi_cur = gi_n; w2_cur = w2_n; act_cur = act_n;
    }
    while (cnt > done) {
        int nb = cnt - done; if (nb > 16) nb = 16;
        process16(nb);
    }

    for (int off = 32; off; off >>= 1) racc += __shfl_xor(racc, off);
    float bi = U1 / (racc + 1e-16f);

    // replicated column-max: replica by block — per-address chains /NREP
    unsigned long long* ck = colkeyR + (size_t)(blockIdx.x & (NREP-1)) * N;
    unsigned long long ikey = (unsigned long long)(unsigned)(N - i);
    int np = min(npairs, PAIR_CAP);
    for (int t = lane; t < np; t += 64) {
        float v = sK[w][t] * bi;
        if (v > 0.f) {
            unsigned long long key = ((unsigned long long)__float_as_uint(v) << 32) | ikey;
            atomicMax(&ck[sJ[w][t]], key);
        }
    }
}

// ---------------- decode replica-max -> winner atomics (softmax-on-demand); wave flags ----------------
__global__ void k_post(const unsigned long long* __restrict__ colkeyR,
                       const float* __restrict__ sv_prob, const int* __restrict__ gt,
                       int* __restrict__ winnerHi, int* __restrict__ winnerLo,
                       int* __restrict__ flags) {
    int j = blockIdx.x * 256 + threadIdx.x;
    int lane = threadIdx.x & 63;
    bool valid = j < N;
    float vv = 0.f; int bidx = 0;
    if (valid) {
        unsigned long long key = 0ull;
        #pragma unroll
        for (int r = 0; r < NREP; ++r) {
            unsigned long long k = colkeyR[(size_t)r*N + j];
            if (k > key) key = k;
        }
        bidx = key ? (N - (int)(key & 0xffffffffull)) : 0;
        const float* p = sv_prob + bidx*OCH;
        float m = -1e30f;
        for (int c = 0; c < OCH; ++c) m = fmaxf(m, p[c]);
        float ssum = 0.f, eg = 0.f; int g = gt[j];
        for (int c = 0; c < OCH; ++c) { float e = expf(p[c] - m); ssum += e; if (c == g) eg = e; }
        vv = eg / ssum;
    }
    bool hi = valid && (vv > 0.1f);
    bool nothi = valid && !(vv > 0.1f);
    bool lo = valid && (vv > 0.0f);
    bool notlo = valid && !(vv > 0.0f);
    if (hi) atomicMax(&winnerHi[bidx], j);
    if (lo) atomicMax(&winnerLo[bidx], j);
    unsigned long long m0 = __ballot(hi);
    unsigned long long m1 = __ballot(nothi);
    unsigned long long m2 = __ballot(notlo);
    if (lane == 0) {
        if (m0) atomicOr(&flags[0], 1);
        if (m1) atomicOr(&flags[1], 1);
        if (m2) atomicOr(&flags[2], 1);
    }
}

// ---------------- final: blocks 0-7 rowsout, block 8 trust, blocks 9+ passthrough copies ----------------
__global__ void __launch_bounds__(1024) k_final(
    const int* __restrict__ winnerHi, const int* __restrict__ winnerLo,
    const int* __restrict__ flags, const int* __restrict__ gt,
    const float* __restrict__ sv_prob,
    const float* __restrict__ mf, const float* __restrict__ ori,
    float* __restrict__ o_svp, float* __restrict__ o_pre,
    float* __restrict__ out0, float* __restrict__ out5,
    float* __restrict__ o_mf, float* __restrict__ o_ori) {
    int bx = blockIdx.x, tid = threadIdx.x;
    if (bx < 8) {
        const int* winner = flags[0] ? winnerHi : winnerLo;
        int i = bx*1024 + tid;
        if (i >= N) return;
        int w = winner[i];
        if (w >= 0) {
            int g = gt[w];
            for (int c = 0; c < OCH; ++c) o_svp[i*OCH + c] = (c == g) ? 1.f : 0.f;
            o_pre[i] = (float)g;
        } else {
            const float* p = sv_prob + i*OCH;
            float m = -1e30f;
            for (int c = 0; c < OCH; ++c) m = fmaxf(m, p[c]);
            float e[OCH]; float ssum = 0.f;
            for (int c = 0; c < OCH; ++c) { e[c] = expf(p[c] - m); ssum += e[c]; }
            float best = e[0] / ssum; int pidx = 0;
            o_svp[i*OCH] = best;
            for (int c = 1; c < OCH; ++c) {
                float r = e[c] / ssum;
                o_svp[i*OCH + c] = r;
                if (r > best) { best = r; pidx = c; }
            }
            o_pre[i] = (float)pidx;
        }
    } else if (bx == 8) {
        __shared__ int wsum[16];
        const int* winner = flags[0] ? winnerHi : winnerLo;
        int off = flags[0] ? (flags[1] ? 1 : 0) : (flags[2] ? 1 : 0);
        for (int p = tid; p < N; p += 1024) { out0[p] = -1.f; out5[p] = -1.f; }
        __syncthreads();
        int base = 0;
        for (int round = 0; round < N; round += 1024) {
            int i = round + tid;
            int pres = (i < N && winner[i] >= 0) ? 1 : 0;
            unsigned long long mask = __ballot(pres);
            int lane = tid & 63;
            int wv = tid >> 6;
            int excl = (lane == 0) ? 0 : __popcll(mask & (~0ull >> (64 - lane)));
            if (lane == 0) wsum[wv] = __popcll(mask);
            __syncthreads();
            int wpre = 0, tot = 0;
            for (int t = 0; t < 16; ++t) { if (t < wv) wpre += wsum[t]; tot += wsum[t]; }
            int pos = base + wpre + excl + off;
            if (pres && pos < N) { out0[pos] = (float)i; out5[pos] = (float)i; }
            base += tot;
            __syncthreads();
        }
    } else {
        const float4* mf4 = (const float4*)mf;
        const float4* ori4 = (const float4*)ori;
        float4* omf4 = (float4*)o_mf;
        float4* oori4 = (float4*)o_ori;
        int t0 = (bx-9)*1024 + tid;
        for (int t = t0; t < 198000; t += 51*1024) {
            if (t < 192000) omf4[t] = mf4[t];
            else oori4[t-192000] = ori4[t-192000];
        }
    }
}

// ---------------- launch ----------------
extern "C" void kernel_launch(void* const* d_in, const int* in_sizes, int n_in,
                              void* d_out, int out_size, void* d_ws, size_t ws_size,
                              hipStream_t stream) {
    const float* sur_feat   = (const float*)d_in[0];
    const float* sur_coords = (const float*)d_in[1];
    const int*   sur_gt     = (const int*)d_in[2];
    const float* sv_prob    = (const float*)d_in[3];
    const float* mean_feat  = (const float*)d_in[4];
    const float* ori        = (const float*)d_in[5];
    const float* posses     = (const float*)d_in[6];

    float* out = (float*)d_out;
    float* o_trust  = out;
    float* o_mf     = out + 8000;
    float* o_ori    = out + 776000;
    float* o_pre    = out + 800000;
    float* o_svp    = out + 808000;
    float* o_trust2 = out + 960000;

    float* w = (float*)d_ws;
    // 16B-aligned region
    float4* alN = (float4*)w;      w += 4*N;
    float4* alR = (float4*)w;      w += 4*N;
    unsigned long long* colkeyR = (unsigned long long*)w;  w += 2*NREP*N;   // 8 replicas × 8000 u64
    // scalar region
    float* w2 = w;                 w += N;
    float* w2R = w;                w += N;
    int* cellB = (int*)w;          w += N;
    int* histB = (int*)w;          w += HSZ;     // [chunk][cell]
    int* flags = (int*)w;          w += 8;
    int* csB = (int*)w;            w += 1008;
    int* idBR = (int*)w;           w += N;
    int* winnerHi = (int*)w;       w += N;       // contiguous with winnerLo (int4-inited)
    int* winnerLo = (int*)w;       w += N;

    dim3 b256(256);

    k_prep<<<80, b256, 0, stream>>>(sur_feat, sur_coords, posses,
                                    w2, alN, cellB, histB,
                                    (int4*)colkeyR, (int4*)winnerHi, flags);
    k_scatter<<<32, b256, 0, stream>>>(cellB, histB, w2, alN, idBR, w2R, alR, csB);
    k_pairs<<<N/4, b256, 0, stream>>>((const float4*)mean_feat, ori, alR, w2R,
                                      (const float4*)sur_feat, idBR, csB, colkeyR);
    k_post<<<32, b256, 0, stream>>>(colkeyR, sv_prob, sur_gt, winnerHi, winnerLo, flags);
    k_final<<<60, 1024, 0, stream>>>(winnerHi, winnerLo, flags, sur_gt, sv_prob,
                                     mean_feat, ori,
                                     o_svp, o_pre, o_trust, o_trust2, o_mf, o_ori);
}